// Round 4
// baseline (214.868 us; speedup 1.0000x reference)
//
#include <hip/hip_runtime.h>
#include <math.h>

// Problem constants: T=4, V=2, L=3, N=4000, D=256, TEMP=0.5
#define DD 256
#define NV 2
#define NL 3
#define NNODE 4000
// Row table: B-rows (anchors at all 6 (x,y)) then C-rows (cross negatives).
#define NROWS_B 8640
#define NROWS 10800
#define NANCH 1440
// ws layout (floats): [0, NROWS*128) = z as bf16 (NROWS x 256 ushort)
//                     [ACC_OFF, +1440) pos | [+1440, +2880) neg | [+2880] int counter
//                     [WP_OFF, +65536) frag-ordered bf16 W' (131072 ushort)
#define ACC_OFF (10800L * 128)
#define CNT_IDX (ACC_OFF + 2 * NANCH)
#define WP_OFF (ACC_OFF + 2 * NANCH + 4)
#define XPAD 260
#define NBLK_SIM 96

typedef __attribute__((ext_vector_type(8))) short short8;
typedef __attribute__((ext_vector_type(4))) short short4v;
typedef __attribute__((ext_vector_type(4))) float f32x4;

__device__ __forceinline__ unsigned short f2bf(float f) {
  unsigned u = __float_as_uint(f);
  u += 0x7fff + ((u >> 16) & 1);   // RNE
  return (unsigned short)(u >> 16);
}

__device__ __forceinline__ int tb_B(int t) { return (t < 2) ? t * 3600 : 7200 + (t - 2) * 720; }
__device__ __forceinline__ int tb_C(int t) { return (t < 2) ? t * 900 : 1800 + (t - 2) * 180; }
__device__ __forceinline__ int anch_base(int t, int vl) {
  return ((t < 2) ? t * 600 : 1200 + (t - 2) * 120) + vl * ((t < 2) ? 100 : 20);
}

// Map flat row id u -> source offset (floats) in E. Wave-uniform.
__device__ __forceinline__ long row_src(int u, const int* __restrict__ ip,
                                        const int* __restrict__ ir,
                                        const int* __restrict__ npg,
                                        const int* __restrict__ nrg) {
  int t, x, y, node;
  if (u < NROWS_B) {
    int S, u2;
    if (u < 7200) { t = u / 3600; u2 = u - t * 3600; S = 100; }
    else { int w = u - 7200; t = 2 + w / 720; u2 = w % 720; S = 20; }
    int s = u2 % S; int t1 = u2 / S;
    int l = t1 % NL; int t2 = t1 / NL;
    int v = t2 % NV; int xy = t2 / NV;
    x = xy / NL; y = xy % NL;
    if (t < 2) node = ip[((t * NV + v) * NL + l) * 100 + s];
    else       node = ir[(((t - 2) * NV + v) * NL + l) * 20 + s];
  } else {
    int w = u - NROWS_B;
    int K, u2;
    if (w < 1800) { t = w / 900; u2 = w % 900; K = 50; }
    else { int w2 = w - 1800; t = 2 + w2 / 180; u2 = w2 % 180; K = 10; }
    int k = u2 % K; int t1 = u2 / K;
    int l = t1 % NL; int t2 = t1 / NL;
    int v = t2 % NV; int o = t2 / NV;
    if (t < 2) node = npg[(((t * NV + v) * NL + l) * 3 + o) * 50 + k];
    else       node = nrg[((((t - 2) * NV + v) * NL + l) * 3 + o) * 10 + k];
    int ot = (o < t) ? o : o + 1;
    t = ot; x = v; y = l;
  }
  return ((((long)t * NV + x) * NL + y) * NNODE + node) * DD;
}

// K-1: build frag-ordered bf16 W' and zero pos/neg accumulators + counter.
__global__ __launch_bounds__(256) void k_prep(const float* __restrict__ W1,
                                              const float* __restrict__ W2,
                                              float* __restrict__ ws) {
  int tid = blockIdx.x * 256 + threadIdx.x;   // grid 64 -> 16384 threads
  if (tid < 2 * NANCH + 4) ws[ACC_OFF + tid] = 0.0f;
  int st = tid >> 13, rem = tid & 8191;
  int cg = rem >> 9, kstep = (rem >> 6) & 7, lane = rem & 63;
  const float* W = st ? W2 : W1;
  int col = cg * 16 + (lane & 15);
  int k0 = kstep * 32 + (lane >> 4) * 8;
  unsigned short v[8] __attribute__((aligned(16)));
#pragma unroll
  for (int j = 0; j < 8; ++j) v[j] = f2bf(W[col * DD + k0 + j]);
  unsigned short* wp = (unsigned short*)(ws + WP_OFF);
  *(uint4*)(wp + (long)tid * 8) = *(const uint4*)v;
}

// K1: MFMA projection. Block = 32 rows, 4 waves; wave (rhalf,chalf) computes
// rows rhalf*16+[0,16) x cols chalf*128+[0,128). Stores z as bf16.
__global__ __launch_bounds__(256) void k_proj(const float* __restrict__ E,
                                              const float* __restrict__ b1,
                                              const float* __restrict__ b2,
                                              const int* __restrict__ ip,
                                              const int* __restrict__ ir,
                                              const int* __restrict__ npg,
                                              const int* __restrict__ nrg,
                                              float* __restrict__ ws) {
  __shared__ unsigned short Xs[32][XPAD];
  __shared__ unsigned short Hs[32][XPAD];
  __shared__ float ssbuf[2][32];
  const int tid = threadIdx.x;
  const int u0 = blockIdx.x * 32;
  const int wv = tid >> 6, l64 = tid & 63;
  const int quad = l64 >> 4, l15 = l64 & 15;
  const int rhalf = wv & 1, chalf = wv >> 1;
  const int rb = rhalf * 16, cb = chalf * 128;
  const unsigned short* wp = (const unsigned short*)(ws + WP_OFF);
  unsigned short* zb = (unsigned short*)ws;

  for (int i = 0; i < 8; ++i) {
    int r = wv * 8 + i;
    int u = u0 + r;
    float4 val = make_float4(0.f, 0.f, 0.f, 0.f);
    if (u < NROWS) {
      long src = row_src(u, ip, ir, npg, nrg);   // wave-uniform
      val = *(const float4*)(E + src + l64 * 4);
    }
    unsigned short h[4] __attribute__((aligned(8)));
    h[0] = f2bf(val.x); h[1] = f2bf(val.y); h[2] = f2bf(val.z); h[3] = f2bf(val.w);
    *(uint2*)(&Xs[r][l64 * 4]) = *(const uint2*)h;
  }

  f32x4 acc[8];
  // ---- stage 1: H = relu(X @ W1^T + b1) ----
#pragma unroll
  for (int cg = 0; cg < 8; ++cg) {
    float bv = b1[cb + cg * 16 + l15];
    acc[cg] = (f32x4){bv, bv, bv, bv};
  }
  __syncthreads();
#pragma unroll
  for (int ks = 0; ks < 8; ++ks) {
    const unsigned short* ap = &Xs[rb + l15][ks * 32 + quad * 8];
    short4v alo = *(const short4v*)(ap);
    short4v ahi = *(const short4v*)(ap + 4);
    short8 a = __builtin_shufflevector(alo, ahi, 0, 1, 2, 3, 4, 5, 6, 7);
#pragma unroll
    for (int cg = 0; cg < 8; ++cg) {
      short8 b = *(const short8*)(wp + ((long)(((chalf * 8 + cg) * 8 + ks) * 64 + l64)) * 8);
      acc[cg] = __builtin_amdgcn_mfma_f32_16x16x32_bf16(a, b, acc[cg], 0, 0, 0);
    }
  }
#pragma unroll
  for (int cg = 0; cg < 8; ++cg) {
    int col = cb + cg * 16 + l15;
#pragma unroll
    for (int reg = 0; reg < 4; ++reg) {
      int row = rb + quad * 4 + reg;                 // C/D: col=lane&15, row=quad*4+reg
      Hs[row][col] = f2bf(fmaxf(acc[cg][reg], 0.0f));
    }
  }
  // ---- stage 2: Z = H @ W2^T + b2 ----
#pragma unroll
  for (int cg = 0; cg < 8; ++cg) {
    float bv = b2[cb + cg * 16 + l15];
    acc[cg] = (f32x4){bv, bv, bv, bv};
  }
  __syncthreads();
#pragma unroll
  for (int ks = 0; ks < 8; ++ks) {
    const unsigned short* ap = &Hs[rb + l15][ks * 32 + quad * 8];
    short4v alo = *(const short4v*)(ap);
    short4v ahi = *(const short4v*)(ap + 4);
    short8 a = __builtin_shufflevector(alo, ahi, 0, 1, 2, 3, 4, 5, 6, 7);
#pragma unroll
    for (int cg = 0; cg < 8; ++cg) {
      short8 b = *(const short8*)(wp + ((long)((16 + chalf * 8 + cg) * 8 + ks) * 64 + l64) * 8);
      acc[cg] = __builtin_amdgcn_mfma_f32_16x16x32_bf16(a, b, acc[cg], 0, 0, 0);
    }
  }
  // ---- normalize (fp32) + store bf16 z ----
  float ss[4];
#pragma unroll
  for (int reg = 0; reg < 4; ++reg) {
    float s = 0.f;
#pragma unroll
    for (int cg = 0; cg < 8; ++cg) s = fmaf(acc[cg][reg], acc[cg][reg], s);
    ss[reg] = s;
  }
#pragma unroll
  for (int m = 1; m < 16; m <<= 1) {
#pragma unroll
    for (int reg = 0; reg < 4; ++reg) ss[reg] += __shfl_xor(ss[reg], m, 64);
  }
  if (l15 == 0) {
#pragma unroll
    for (int reg = 0; reg < 4; ++reg) ssbuf[chalf][rb + quad * 4 + reg] = ss[reg];
  }
  __syncthreads();
#pragma unroll
  for (int reg = 0; reg < 4; ++reg) {
    int row = rb + quad * 4 + reg;
    int u = u0 + row;
    if (u < NROWS) {
      float tot = ssbuf[0][row] + ssbuf[1][row];
      float sc = 1.0f / fmaxf(sqrtf(tot), 1e-12f);
#pragma unroll
      for (int cg = 0; cg < 8; ++cg)
        zb[(long)u * DD + cb + cg * 16 + l15] = f2bf(acc[cg][reg] * sc);
    }
  }
}

// K2: fused sims + loss. Grid 96 = (t<2: 2x6x6 chunks) + (t>=2: 2x6x2 chunks).
// Per block: anchors S x partner-chunk(128) of Ptot=6S+3K; MFMA 16x16x32 bf16
// with A/B frags read directly from global z (bf16). pos = diag of xy!=vl
// B-blocks; neg = off-diag of xy==vl block + all C rows. Device-scope done
// counter; last block computes mean(-log(pos/(pos+neg))).
__global__ __launch_bounds__(256) void k_sim(float* __restrict__ ws,
                                             float* __restrict__ out) {
  __shared__ float negL[112];
  __shared__ float red[256];
  __shared__ int lastFlag;
  const unsigned short* zb = (const unsigned short*)ws;
  float* posG = ws + ACC_OFF;
  float* negG = ws + ACC_OFF + NANCH;
  int* cnt = (int*)(ws + CNT_IDX);

  const int b = blockIdx.x;
  int t, vl, c;
  if (b < 72) { t = b / 36; int r = b % 36; vl = r / 6; c = r % 6; }
  else { int q = b - 72; t = 2 + q / 12; int r2 = q % 12; vl = r2 / 2; c = r2 % 2; }
  const int v = vl / NL, l = vl % NL;
  const int S = (t < 2) ? 100 : 20, K = (t < 2) ? 50 : 10;
  const int Ptot = 6 * S + 3 * K;              // 750 / 150
  const int q0 = c * 128;
  const int rem = Ptot - q0;
  const int NT = ((rem < 128 ? rem : 128) + 15) / 16;
  const int MT = (S + 15) / 16;                // 7 / 2
  const int tid = threadIdx.x;
  const int wv = tid >> 6, l64 = tid & 63;
  const int quad = l64 >> 4, l15 = l64 & 15;
  const int ab = anch_base(t, vl);
  const int rowZbase = tb_B(t) + ((vl * NV + v) * NL + l) * S;

  for (int mt = wv; mt < MT; mt += 4) {
    int am = mt * 16 + l15;
    int amc = (am < S) ? am : (S - 1);
    const unsigned short* abase = zb + (long)(rowZbase + amc) * DD + quad * 8;
    short8 afr[8];
#pragma unroll
    for (int ks = 0; ks < 8; ++ks) afr[ks] = *(const short8*)(abase + ks * 32);
    float negAcc[4] = {0.f, 0.f, 0.f, 0.f};
    for (int nt = 0; nt < NT; ++nt) {
      int qg = q0 + nt * 16 + l15;
      bool vq = (qg < Ptot);
      int qc = vq ? qg : 0;
      int rowb, xy = -1, j = -1;
      if (qc < 6 * S) {
        xy = qc / S; j = qc - xy * S;
        rowb = tb_B(t) + ((xy * NV + v) * NL + l) * S + j;
      } else {
        int q2 = qc - 6 * S; int o = q2 / K, k2 = q2 - o * K;
        rowb = NROWS_B + tb_C(t) + ((o * NV + v) * NL + l) * K + k2;
      }
      const unsigned short* bbase = zb + (long)rowb * DD + quad * 8;
      f32x4 acc = {0.f, 0.f, 0.f, 0.f};
#pragma unroll
      for (int ks = 0; ks < 8; ++ks) {
        short8 bfr = *(const short8*)(bbase + ks * 32);
        acc = __builtin_amdgcn_mfma_f32_16x16x32_bf16(afr[ks], bfr, acc, 0, 0, 0);
      }
      // tile epilogue: element (row = mt*16+quad*4+r, col = qg)
#pragma unroll
      for (int r = 0; r < 4; ++r) {
        int a = mt * 16 + quad * 4 + r;
        if (!vq || a >= S) continue;
        float e = expf(2.0f * acc[r]);
        if (xy >= 0) {
          if (xy == vl) { if (j != a) negAcc[r] += e; }
          else if (j == a) atomicAdd(&posG[ab + a], e);
        } else {
          negAcc[r] += e;
        }
      }
    }
#pragma unroll
    for (int m = 1; m < 16; m <<= 1) {
#pragma unroll
      for (int r = 0; r < 4; ++r) negAcc[r] += __shfl_xor(negAcc[r], m, 64);
    }
    if (l15 == 0) {
#pragma unroll
      for (int r = 0; r < 4; ++r) negL[mt * 16 + quad * 4 + r] = negAcc[r];
    }
  }
  __syncthreads();
  for (int a = tid; a < S; a += 256) atomicAdd(&negG[ab + a], negL[a]);
  __threadfence();
  __syncthreads();
  if (tid == 0) {
    int old = atomicAdd(cnt, 1);
    lastFlag = (old == NBLK_SIM - 1) ? 1 : 0;
  }
  __syncthreads();
  if (lastFlag) {
    float sum = 0.f;
    for (int i = tid; i < NANCH; i += 256) {
      float p = atomicAdd(&posG[i], 0.0f);   // device-scope coherent read
      float n = atomicAdd(&negG[i], 0.0f);
      sum += -logf(p / (p + n));
    }
    red[tid] = sum;
    __syncthreads();
    for (int s = 128; s > 0; s >>= 1) {
      if (tid < s) red[tid] += red[tid + s];
      __syncthreads();
    }
    if (tid == 0) out[0] = red[0] / (float)NANCH;
  }
}

extern "C" void kernel_launch(void* const* d_in, const int* in_sizes, int n_in,
                              void* d_out, int out_size, void* d_ws, size_t ws_size,
                              hipStream_t stream) {
  const float* E  = (const float*)d_in[0];
  const float* W1 = (const float*)d_in[1];
  const float* b1 = (const float*)d_in[2];
  const float* W2 = (const float*)d_in[3];
  const float* b2 = (const float*)d_in[4];
  const int* ip  = (const int*)d_in[5];
  const int* ir  = (const int*)d_in[6];
  const int* npg = (const int*)d_in[7];
  const int* nrg = (const int*)d_in[8];
  float* ws = (float*)d_ws;   // ~5.9 MB used
  float* out = (float*)d_out;

  hipLaunchKernelGGL(k_prep, dim3(64), dim3(256), 0, stream, W1, W2, ws);
  hipLaunchKernelGGL(k_proj, dim3((NROWS + 31) / 32), dim3(256), 0, stream,
                     E, b1, b2, ip, ir, npg, nrg, ws);
  hipLaunchKernelGGL(k_sim, dim3(NBLK_SIM), dim3(256), 0, stream, ws, out);
}

// Round 5
// 203.177 us; speedup vs baseline: 1.0575x; 1.0575x over previous
//
#include <hip/hip_runtime.h>
#include <math.h>

// Problem constants: T=4, V=2, L=3, N=4000, D=256, TEMP=0.5
#define DD 256
#define NV 2
#define NL 3
#define NNODE 4000
// Row table: B-rows (anchors at all 6 (x,y)) then C-rows (cross negatives).
#define NROWS_B 8640
#define NROWS 10800
#define NANCH 1440
// ws layout (floats): [0, NROWS*128) = z as bf16 (NROWS x 256 ushort)
//                     [ACC_OFF, +1440) pos | [+1440, +2880) neg | [+2880] int counter
//                     [WP_OFF, +65536) frag-ordered bf16 W' (131072 ushort)
#define ACC_OFF (10800L * 128)
#define CNT_IDX (ACC_OFF + 2 * NANCH)
#define WP_OFF (ACC_OFF + 2 * NANCH + 4)
#define XPAD 260
// k_sim wave-tasks: t<2: 2*6*(7 mt)*(24 chunks of 32) = 2016; t>=2: 2*6*2*5 = 120
#define NTASK 2136
#define NBLK_SIM (NTASK / 4)   // 534 blocks, 4 waves each

typedef __attribute__((ext_vector_type(8))) short short8;
typedef __attribute__((ext_vector_type(4))) short short4v;
typedef __attribute__((ext_vector_type(4))) float f32x4;

__device__ __forceinline__ unsigned short f2bf(float f) {
  unsigned u = __float_as_uint(f);
  u += 0x7fff + ((u >> 16) & 1);   // RNE
  return (unsigned short)(u >> 16);
}

__device__ __forceinline__ int tb_B(int t) { return (t < 2) ? t * 3600 : 7200 + (t - 2) * 720; }
__device__ __forceinline__ int tb_C(int t) { return (t < 2) ? t * 900 : 1800 + (t - 2) * 180; }
__device__ __forceinline__ int anch_base(int t, int vl) {
  return ((t < 2) ? t * 600 : 1200 + (t - 2) * 120) + vl * ((t < 2) ? 100 : 20);
}

// Map flat row id u -> source offset (floats) in E. Wave-uniform.
__device__ __forceinline__ long row_src(int u, const int* __restrict__ ip,
                                        const int* __restrict__ ir,
                                        const int* __restrict__ npg,
                                        const int* __restrict__ nrg) {
  int t, x, y, node;
  if (u < NROWS_B) {
    int S, u2;
    if (u < 7200) { t = u / 3600; u2 = u - t * 3600; S = 100; }
    else { int w = u - 7200; t = 2 + w / 720; u2 = w % 720; S = 20; }
    int s = u2 % S; int t1 = u2 / S;
    int l = t1 % NL; int t2 = t1 / NL;
    int v = t2 % NV; int xy = t2 / NV;
    x = xy / NL; y = xy % NL;
    if (t < 2) node = ip[((t * NV + v) * NL + l) * 100 + s];
    else       node = ir[(((t - 2) * NV + v) * NL + l) * 20 + s];
  } else {
    int w = u - NROWS_B;
    int K, u2;
    if (w < 1800) { t = w / 900; u2 = w % 900; K = 50; }
    else { int w2 = w - 1800; t = 2 + w2 / 180; u2 = w2 % 180; K = 10; }
    int k = u2 % K; int t1 = u2 / K;
    int l = t1 % NL; int t2 = t1 / NL;
    int v = t2 % NV; int o = t2 / NV;
    if (t < 2) node = npg[(((t * NV + v) * NL + l) * 3 + o) * 50 + k];
    else       node = nrg[((((t - 2) * NV + v) * NL + l) * 3 + o) * 10 + k];
    int ot = (o < t) ? o : o + 1;
    t = ot; x = v; y = l;
  }
  return ((((long)t * NV + x) * NL + y) * NNODE + node) * DD;
}

// K-1: build frag-ordered bf16 W' and zero pos/neg accumulators + counter.
__global__ __launch_bounds__(256) void k_prep(const float* __restrict__ W1,
                                              const float* __restrict__ W2,
                                              float* __restrict__ ws) {
  int tid = blockIdx.x * 256 + threadIdx.x;   // grid 64 -> 16384 threads
  if (tid < 2 * NANCH + 4) ws[ACC_OFF + tid] = 0.0f;
  int st = tid >> 13, rem = tid & 8191;
  int cg = rem >> 9, kstep = (rem >> 6) & 7, lane = rem & 63;
  const float* W = st ? W2 : W1;
  int col = cg * 16 + (lane & 15);
  int k0 = kstep * 32 + (lane >> 4) * 8;
  unsigned short v[8] __attribute__((aligned(16)));
#pragma unroll
  for (int j = 0; j < 8; ++j) v[j] = f2bf(W[col * DD + k0 + j]);
  unsigned short* wp = (unsigned short*)(ws + WP_OFF);
  *(uint4*)(wp + (long)tid * 8) = *(const uint4*)v;
}

// K1 v4: MFMA projection, 16 rows/block, 675 blocks. The 4 waves split COLUMNS
// (wave c: rows [0,16) x cols c*64+[0,64), 4 cg each) so per-wave serial chain
// is half of v3 and grid doubles -> ~10 waves/CU for latency hiding.
__global__ __launch_bounds__(256) void k_proj(const float* __restrict__ E,
                                              const float* __restrict__ b1,
                                              const float* __restrict__ b2,
                                              const int* __restrict__ ip,
                                              const int* __restrict__ ir,
                                              const int* __restrict__ npg,
                                              const int* __restrict__ nrg,
                                              float* __restrict__ ws) {
  __shared__ unsigned short Xs[16][XPAD];
  __shared__ unsigned short Hs[16][XPAD];
  __shared__ float ssbuf[4][16];
  const int tid = threadIdx.x;
  const int u0 = blockIdx.x * 16;
  const int wv = tid >> 6, l64 = tid & 63;
  const int quad = l64 >> 4, l15 = l64 & 15;
  const int cb = wv * 64;
  const unsigned short* wp = (const unsigned short*)(ws + WP_OFF);
  unsigned short* zb = (unsigned short*)ws;

  // gather 4 rows per wave, fp32 -> bf16
  for (int i = 0; i < 4; ++i) {
    int r = wv * 4 + i;
    int u = u0 + r;
    long src = row_src(u, ip, ir, npg, nrg);   // wave-uniform
    float4 val = *(const float4*)(E + src + l64 * 4);
    unsigned short h[4] __attribute__((aligned(8)));
    h[0] = f2bf(val.x); h[1] = f2bf(val.y); h[2] = f2bf(val.z); h[3] = f2bf(val.w);
    *(uint2*)(&Xs[r][l64 * 4]) = *(const uint2*)h;
  }

  f32x4 acc[4];
  // ---- stage 1: H = relu(X @ W1^T + b1) ----
#pragma unroll
  for (int cg = 0; cg < 4; ++cg) {
    float bv = b1[cb + cg * 16 + l15];
    acc[cg] = (f32x4){bv, bv, bv, bv};
  }
  __syncthreads();
#pragma unroll
  for (int ks = 0; ks < 8; ++ks) {
    const unsigned short* ap = &Xs[l15][ks * 32 + quad * 8];
    short4v alo = *(const short4v*)(ap);
    short4v ahi = *(const short4v*)(ap + 4);
    short8 a = __builtin_shufflevector(alo, ahi, 0, 1, 2, 3, 4, 5, 6, 7);
#pragma unroll
    for (int cg = 0; cg < 4; ++cg) {
      short8 b = *(const short8*)(wp + ((long)(((wv * 4 + cg) * 8 + ks) * 64 + l64)) * 8);
      acc[cg] = __builtin_amdgcn_mfma_f32_16x16x32_bf16(a, b, acc[cg], 0, 0, 0);
    }
  }
  __syncthreads();   // Xs reads done before Hs overwrites? (separate buffers; sync for Hs write/read order)
#pragma unroll
  for (int cg = 0; cg < 4; ++cg) {
    int col = cb + cg * 16 + l15;
#pragma unroll
    for (int reg = 0; reg < 4; ++reg) {
      int row = quad * 4 + reg;                 // C/D: col=lane&15, row=quad*4+reg
      Hs[row][col] = f2bf(fmaxf(acc[cg][reg], 0.0f));
    }
  }
  // ---- stage 2: Z = H @ W2^T + b2 ----
#pragma unroll
  for (int cg = 0; cg < 4; ++cg) {
    float bv = b2[cb + cg * 16 + l15];
    acc[cg] = (f32x4){bv, bv, bv, bv};
  }
  __syncthreads();
#pragma unroll
  for (int ks = 0; ks < 8; ++ks) {
    const unsigned short* ap = &Hs[l15][ks * 32 + quad * 8];
    short4v alo = *(const short4v*)(ap);
    short4v ahi = *(const short4v*)(ap + 4);
    short8 a = __builtin_shufflevector(alo, ahi, 0, 1, 2, 3, 4, 5, 6, 7);
#pragma unroll
    for (int cg = 0; cg < 4; ++cg) {
      short8 b = *(const short8*)(wp + ((long)((16 + wv * 4 + cg) * 8 + ks) * 64 + l64) * 8);
      acc[cg] = __builtin_amdgcn_mfma_f32_16x16x32_bf16(a, b, acc[cg], 0, 0, 0);
    }
  }
  // ---- normalize (fp32, cross-wave partials) + store bf16 z ----
  float ss[4];
#pragma unroll
  for (int reg = 0; reg < 4; ++reg) {
    float s = 0.f;
#pragma unroll
    for (int cg = 0; cg < 4; ++cg) s = fmaf(acc[cg][reg], acc[cg][reg], s);
    ss[reg] = s;
  }
#pragma unroll
  for (int m = 1; m < 16; m <<= 1) {
#pragma unroll
    for (int reg = 0; reg < 4; ++reg) ss[reg] += __shfl_xor(ss[reg], m, 64);
  }
  if (l15 == 0) {
#pragma unroll
    for (int reg = 0; reg < 4; ++reg) ssbuf[wv][quad * 4 + reg] = ss[reg];
  }
  __syncthreads();
#pragma unroll
  for (int reg = 0; reg < 4; ++reg) {
    int row = quad * 4 + reg;
    int u = u0 + row;
    float tot = ssbuf[0][row] + ssbuf[1][row] + ssbuf[2][row] + ssbuf[3][row];
    float sc = 1.0f / fmaxf(sqrtf(tot), 1e-12f);
#pragma unroll
    for (int cg = 0; cg < 4; ++cg)
      zb[(long)u * DD + cb + cg * 16 + l15] = f2bf(acc[cg][reg] * sc);
  }
}

// K2 v2: fused sims + loss, one WAVE = one (t,vl,mt,chunk-of-32) task.
// 2136 tasks / 534 blocks -> ~8 waves/CU. MFMA 16x16x32 bf16, frags straight
// from global bf16 z. pos = diag of xy!=vl blocks; neg = off-diag xy==vl +
// cross rows. Device-scope counter; last block reduces the 1440 losses.
__global__ __launch_bounds__(256) void k_sim(float* __restrict__ ws,
                                             float* __restrict__ out) {
  __shared__ float red[256];
  __shared__ int lastFlag;
  const unsigned short* zb = (const unsigned short*)ws;
  float* posG = ws + ACC_OFF;
  float* negG = ws + ACC_OFF + NANCH;
  int* cnt = (int*)(ws + CNT_IDX);

  const int tid = threadIdx.x;
  const int wv = tid >> 6, l64 = tid & 63;
  const int quad = l64 >> 4, l15 = l64 & 15;
  const int task = blockIdx.x * 4 + wv;

  int t, vl, mt, c;
  if (task < 2016) { t = task / 1008; int r = task % 1008;
                     vl = r / 168; int r2 = r % 168; mt = r2 / 24; c = r2 % 24; }
  else { int q = task - 2016; t = 2 + q / 60; int r2 = q % 60;
         vl = r2 / 10; int r3 = r2 % 10; mt = r3 / 5; c = r3 % 5; }
  const int v = vl / NL, l = vl % NL;
  const int S = (t < 2) ? 100 : 20, K = (t < 2) ? 50 : 10;
  const int Ptot = 6 * S + 3 * K;              // 750 / 150
  const int ab = anch_base(t, vl);
  const int rowZbase = tb_B(t) + ((vl * NV + v) * NL + l) * S;

  int am = mt * 16 + l15;
  int amc = (am < S) ? am : (S - 1);
  const unsigned short* abase = zb + (long)(rowZbase + amc) * DD + quad * 8;
  short8 afr[8];
#pragma unroll
  for (int ks = 0; ks < 8; ++ks) afr[ks] = *(const short8*)(abase + ks * 32);

  float negAcc[4] = {0.f, 0.f, 0.f, 0.f};
#pragma unroll
  for (int nt = 0; nt < 2; ++nt) {
    int qg = c * 32 + nt * 16 + l15;
    bool vq = (qg < Ptot);
    int qc = vq ? qg : 0;
    int rowb, xy = -1, j = -1;
    if (qc < 6 * S) {
      xy = qc / S; j = qc - xy * S;
      rowb = tb_B(t) + ((xy * NV + v) * NL + l) * S + j;
    } else {
      int q2 = qc - 6 * S; int o = q2 / K, k2 = q2 - o * K;
      rowb = NROWS_B + tb_C(t) + ((o * NV + v) * NL + l) * K + k2;
    }
    const unsigned short* bbase = zb + (long)rowb * DD + quad * 8;
    f32x4 acc = {0.f, 0.f, 0.f, 0.f};
#pragma unroll
    for (int ks = 0; ks < 8; ++ks) {
      short8 bfr = *(const short8*)(bbase + ks * 32);
      acc = __builtin_amdgcn_mfma_f32_16x16x32_bf16(afr[ks], bfr, acc, 0, 0, 0);
    }
    // element (row = mt*16+quad*4+r, col = qg)
#pragma unroll
    for (int r = 0; r < 4; ++r) {
      int a = mt * 16 + quad * 4 + r;
      if (!vq || a >= S) continue;
      float e = expf(2.0f * acc[r]);
      if (xy >= 0) {
        if (xy == vl) { if (j != a) negAcc[r] += e; }
        else if (j == a) atomicAdd(&posG[ab + a], e);
      } else {
        negAcc[r] += e;
      }
    }
  }
  // reduce over the 16 partner-lanes of each quad, add to global neg
#pragma unroll
  for (int m = 1; m < 16; m <<= 1) {
#pragma unroll
    for (int r = 0; r < 4; ++r) negAcc[r] += __shfl_xor(negAcc[r], m, 64);
  }
  if (l15 == 0) {
#pragma unroll
    for (int r = 0; r < 4; ++r) {
      int a = mt * 16 + quad * 4 + r;
      if (a < S) atomicAdd(&negG[ab + a], negAcc[r]);
    }
  }
  __threadfence();
  __syncthreads();
  if (tid == 0) {
    int old = atomicAdd(cnt, 1);
    lastFlag = (old == NBLK_SIM - 1) ? 1 : 0;
  }
  __syncthreads();
  if (lastFlag) {
    float sum = 0.f;
    for (int i = tid; i < NANCH; i += 256) {
      float p = atomicAdd(&posG[i], 0.0f);   // device-scope coherent read
      float n = atomicAdd(&negG[i], 0.0f);
      sum += -logf(p / (p + n));
    }
    red[tid] = sum;
    __syncthreads();
    for (int s = 128; s > 0; s >>= 1) {
      if (tid < s) red[tid] += red[tid + s];
      __syncthreads();
    }
    if (tid == 0) out[0] = red[0] / (float)NANCH;
  }
}

extern "C" void kernel_launch(void* const* d_in, const int* in_sizes, int n_in,
                              void* d_out, int out_size, void* d_ws, size_t ws_size,
                              hipStream_t stream) {
  const float* E  = (const float*)d_in[0];
  const float* W1 = (const float*)d_in[1];
  const float* b1 = (const float*)d_in[2];
  const float* W2 = (const float*)d_in[3];
  const float* b2 = (const float*)d_in[4];
  const int* ip  = (const int*)d_in[5];
  const int* ir  = (const int*)d_in[6];
  const int* npg = (const int*)d_in[7];
  const int* nrg = (const int*)d_in[8];
  float* ws = (float*)d_ws;   // ~5.9 MB used
  float* out = (float*)d_out;

  hipLaunchKernelGGL(k_prep, dim3(64), dim3(256), 0, stream, W1, W2, ws);
  hipLaunchKernelGGL(k_proj, dim3(NROWS / 16), dim3(256), 0, stream,
                     E, b1, b2, ip, ir, npg, nrg, ws);
  hipLaunchKernelGGL(k_sim, dim3(NBLK_SIM), dim3(256), 0, stream, ws, out);
}